// Round 3
// baseline (2218.961 us; speedup 1.0000x reference)
//
#include <hip/hip_runtime.h>
#include <cstdint>

#define B_   64
#define H_   56
#define W_   56
#define C_   128
#define WSZ  7
#define TT   49
#define NN   3136            // H*W
#define MM   (B_ * NN)       // 200704
#define SCALE 0.17677669529663687f

typedef unsigned short u16;

__device__ __forceinline__ float bf2f(u16 u) {
    return __uint_as_float(((unsigned int)u) << 16);
}
__device__ __forceinline__ u16 f2bf(float f) {
    unsigned int u = __float_as_uint(f);
    u += 0x7FFFu + ((u >> 16) & 1u);   // round-to-nearest-even
    return (u16)(u >> 16);
}

// ---------------------------------------------------------------------------
// KA: fused qkv + windowed attention, pure f32 VALU (correctness anchor).
// One block per (batch, window). Writes attn output (f32, image layout) to
// d_out and v (bf16, windowed layout) to ws for the conv kernel.
// LDS: union{ (x^T + w-chunk^T) , scores } + qkv store = 136,856 B
// (gfx950 addressable LDS = 160 KiB).
// ---------------------------------------------------------------------------
struct SA { float xs[128][53]; float wt[128][65]; };   // k-major (transposed)
union  LU { SA a; float sc[4][49][49]; };

__global__ __launch_bounds__(256) void ka_attn(
    const float* __restrict__ x, const float* __restrict__ wqkv,
    u16* __restrict__ vout, float* __restrict__ out)
{
    __shared__ LU lds;
    __shared__ float qkvs[3][49][130];
    const int t   = threadIdx.x;
    const int blk = blockIdx.x;
    const int b_  = blk >> 6, wr = blk & 63;
    const int qy  = wr >> 3, qx = wr & 7;

    // ---- stage x window tokens, transposed to k-major ----
    for (int i = t; i < 49 * 32; i += 256) {
        int tok = i >> 5, c4 = (i & 31) * 4;
        int hh = qy * WSZ + tok / WSZ, ww = qx * WSZ + tok % WSZ;
        float4 fx = *(const float4*)&x[((size_t)b_ * NN + hh * W_ + ww) * C_ + c4];
        lds.a.xs[c4 + 0][tok] = fx.x;
        lds.a.xs[c4 + 1][tok] = fx.y;
        lds.a.xs[c4 + 2][tok] = fx.z;
        lds.a.xs[c4 + 3][tok] = fx.w;
    }

    // ---- qkv = x @ wqkv^T, 6 passes of 64 output channels ----
    for (int p = 0; p < 6; p++) {
        for (int i = t; i < 64 * 32; i += 256) {
            int row = i >> 5, c4 = (i & 31) * 4;
            float4 fw = *(const float4*)&wqkv[((size_t)(p * 64 + row)) * C_ + c4];
            lds.a.wt[c4 + 0][row] = fw.x;
            lds.a.wt[c4 + 1][row] = fw.y;
            lds.a.wt[c4 + 2][row] = fw.z;
            lds.a.wt[c4 + 3][row] = fw.w;
        }
        __syncthreads();
        if (t < 208) {                    // 16 n-groups x 13 tok-groups, 4x4
            int ng = t / 13, tg = t % 13;
            int n0 = ng * 4, tok0 = tg * 4;
            float acc[4][4] = {};
            for (int k = 0; k < 128; k++) {
                float wv[4], xv[4];
#pragma unroll
                for (int a = 0; a < 4; a++) wv[a] = lds.a.wt[k][n0 + a];
#pragma unroll
                for (int b2 = 0; b2 < 4; b2++)
                    xv[b2] = (tok0 + b2 < TT) ? lds.a.xs[k][tok0 + b2] : 0.f;
#pragma unroll
                for (int a = 0; a < 4; a++)
#pragma unroll
                    for (int b2 = 0; b2 < 4; b2++)
                        acc[a][b2] += wv[a] * xv[b2];
            }
#pragma unroll
            for (int a = 0; a < 4; a++) {
                int ngl = p * 64 + n0 + a;
                int tens = ngl >> 7, col = ngl & 127;
#pragma unroll
                for (int b2 = 0; b2 < 4; b2++)
                    if (tok0 + b2 < TT) qkvs[tens][tok0 + b2][col] = acc[a][b2];
            }
        }
        __syncthreads();
    }

    // ---- scores: per head 49x49, micro 4x4 (xs/wt dead -> sc reuses LDS) ----
    for (int idx = t; idx < 676; idx += 256) {   // 4 heads * 169 groups
        int h = idx / 169, r = idx % 169;
        int i0 = (r / 13) * 4, j0 = (r % 13) * 4;
        float acc[4][4] = {};
        for (int d = 0; d < 32; d++) {
            float qv[4], kv[4];
#pragma unroll
            for (int a = 0; a < 4; a++)
                qv[a] = (i0 + a < TT) ? qkvs[0][i0 + a][h * 32 + d] : 0.f;
#pragma unroll
            for (int b2 = 0; b2 < 4; b2++)
                kv[b2] = (j0 + b2 < TT) ? qkvs[1][j0 + b2][h * 32 + d] : 0.f;
#pragma unroll
            for (int a = 0; a < 4; a++)
#pragma unroll
                for (int b2 = 0; b2 < 4; b2++)
                    acc[a][b2] += qv[a] * kv[b2];
        }
#pragma unroll
        for (int a = 0; a < 4; a++)
            if (i0 + a < TT)
#pragma unroll
                for (int b2 = 0; b2 < 4; b2++)
                    if (j0 + b2 < TT)
                        lds.sc[h][i0 + a][j0 + b2] = acc[a][b2] * SCALE;
    }
    __syncthreads();

    // ---- softmax over keys, one thread per (head,row) ----
    for (int idx = t; idx < 196; idx += 256) {
        int h = idx / 49, i = idx % 49;
        float mx = -1e30f;
        for (int j = 0; j < TT; j++) mx = fmaxf(mx, lds.sc[h][i][j]);
        float s = 0.f;
        for (int j = 0; j < TT; j++) {
            float e = __expf(lds.sc[h][i][j] - mx);
            lds.sc[h][i][j] = e;
            s += e;
        }
        float inv = 1.f / s;
        for (int j = 0; j < TT; j++) lds.sc[h][i][j] *= inv;
    }
    __syncthreads();

    // ---- PV: out 49 x 128, micro 4x4; write to d_out (image layout) ----
    for (int idx = t; idx < 416; idx += 256) {   // 13 tok-groups x 32 c-groups
        int tg = idx >> 5, cg = idx & 31;
        int i0 = tg * 4, c0 = cg * 4;
        int h = c0 >> 5;
        float acc[4][4] = {};
        for (int j = 0; j < TT; j++) {
            float pv[4], vv[4];
#pragma unroll
            for (int a = 0; a < 4; a++)
                pv[a] = (i0 + a < TT) ? lds.sc[h][i0 + a][j] : 0.f;
#pragma unroll
            for (int b2 = 0; b2 < 4; b2++) vv[b2] = qkvs[2][j][c0 + b2];
#pragma unroll
            for (int a = 0; a < 4; a++)
#pragma unroll
                for (int b2 = 0; b2 < 4; b2++)
                    acc[a][b2] += pv[a] * vv[b2];
        }
#pragma unroll
        for (int a = 0; a < 4; a++) {
            int tok = i0 + a;
            if (tok < TT) {
                int hh = qy * WSZ + tok / WSZ, ww = qx * WSZ + tok % WSZ;
                size_t orow = (size_t)b_ * NN + hh * W_ + ww;
#pragma unroll
                for (int b2 = 0; b2 < 4; b2++)
                    out[orow * C_ + c0 + b2] = acc[a][b2];
            }
        }
    }

    // ---- store v (bf16, windowed layout) for the conv kernel ----
    for (int i = t; i < 49 * 32; i += 256) {
        int tok = i >> 5, c4 = (i & 31) * 4;
        ushort4 uv;
        uv.x = f2bf(qkvs[2][tok][c4 + 0]);
        uv.y = f2bf(qkvs[2][tok][c4 + 1]);
        uv.z = f2bf(qkvs[2][tok][c4 + 2]);
        uv.w = f2bf(qkvs[2][tok][c4 + 3]);
        *(ushort4*)&vout[((size_t)b_ * NN + wr * TT + tok) * C_ + c4] = uv;
    }
}

// ---------------------------------------------------------------------------
// KB: depthwise 3x3 conv on bf16 v (windowed layout) + f32 bias/weights,
// accumulate f32 into d_out (B,N,C)
// ---------------------------------------------------------------------------
__global__ __launch_bounds__(256) void kb_lim(
    const u16* __restrict__ v, const float* __restrict__ wlim,
    const float* __restrict__ blim, float* __restrict__ out)
{
    int idx = blockIdx.x * 256 + threadIdx.x;     // < MM*C_
    int c  = idx & 127;
    int p  = idx >> 7;
    int ww = p % W_;
    int p2 = p / W_;
    int hh = p2 % H_;
    int b_ = p2 / H_;
    float acc = blim[c];
#pragma unroll
    for (int dy = -1; dy <= 1; dy++) {
        int y = hh + dy;
        if (y < 0 || y >= H_) continue;
        int qy = y / WSZ, ry = y - qy * WSZ;
#pragma unroll
        for (int dx = -1; dx <= 1; dx++) {
            int x2 = ww + dx;
            if (x2 < 0 || x2 >= W_) continue;
            int qx = x2 / WSZ, rx = x2 - qx * WSZ;
            size_t vrow = (size_t)b_ * NN + (qy * 8 + qx) * TT + ry * WSZ + rx;
            acc += bf2f(v[vrow * C_ + c]) * wlim[c * 9 + (dy + 1) * 3 + (dx + 1)];
        }
    }
    out[idx] = out[idx] + acc;
}

// ---------------------------------------------------------------------------
// KC: out = y @ w_proj^T + b_proj, f32 VALU, in-place on d_out.
// Block stages its full 128-row A tile (and W) into LDS before any store.
// ---------------------------------------------------------------------------
__global__ __launch_bounds__(256) void kc_proj(
    float* __restrict__ y, const float* __restrict__ wproj,
    const float* __restrict__ bproj)
{
    __shared__ float As[128][129];
    __shared__ float Ws[128][129];
    const int t  = threadIdx.x;
    const int m0 = blockIdx.x * 128;
    for (int i = t; i < 128 * 32; i += 256) {
        int row = i >> 5, c4 = (i & 31) * 4;
        float4 fa = *(const float4*)&y[((size_t)(m0 + row)) * C_ + c4];
        As[row][c4 + 0] = fa.x; As[row][c4 + 1] = fa.y;
        As[row][c4 + 2] = fa.z; As[row][c4 + 3] = fa.w;
        float4 fw = *(const float4*)&wproj[((size_t)row) * C_ + c4];
        Ws[row][c4 + 0] = fw.x; Ws[row][c4 + 1] = fw.y;
        Ws[row][c4 + 2] = fw.z; Ws[row][c4 + 3] = fw.w;
    }
    __syncthreads();

    const int ty = t >> 4, tx = t & 15;
    const int r0 = ty * 8, c0 = tx * 8;
    float acc[8][8] = {};
    for (int k = 0; k < 128; k++) {
        float av[8], wv[8];
#pragma unroll
        for (int a = 0; a < 8; a++) av[a] = As[r0 + a][k];
#pragma unroll
        for (int b2 = 0; b2 < 8; b2++) wv[b2] = Ws[c0 + b2][k];
#pragma unroll
        for (int a = 0; a < 8; a++)
#pragma unroll
            for (int b2 = 0; b2 < 8; b2++)
                acc[a][b2] += av[a] * wv[b2];
    }
#pragma unroll
    for (int a = 0; a < 8; a++)
#pragma unroll
        for (int b2 = 0; b2 < 8; b2++)
            y[((size_t)(m0 + r0 + a)) * C_ + c0 + b2] = acc[a][b2] + bproj[c0 + b2];
}

extern "C" void kernel_launch(void* const* d_in, const int* in_sizes, int n_in,
                              void* d_out, int out_size, void* d_ws, size_t ws_size,
                              hipStream_t stream)
{
    const float* x     = (const float*)d_in[0];
    const float* wqkv  = (const float*)d_in[1];
    const float* wlim  = (const float*)d_in[2];
    const float* blim  = (const float*)d_in[3];
    const float* wproj = (const float*)d_in[4];
    const float* bproj = (const float*)d_in[5];
    float* out = (float*)d_out;
    u16*   v   = (u16*)d_ws;            // 51.4 MB only

    ka_attn<<<dim3(B_ * 64), 256, 0, stream>>>(x, wqkv, v, out);
    kb_lim <<<dim3(MM * C_ / 256), 256, 0, stream>>>(v, wlim, blim, out);
    kc_proj<<<dim3(MM / 128), 256, 0, stream>>>(out, wproj, bproj);
}

// Round 5
// 583.171 us; speedup vs baseline: 3.8050x; 3.8050x over previous
//
#include <hip/hip_runtime.h>
#include <cstdint>

#define B_   64
#define H_   56
#define W_   56
#define C_   128
#define WSZ  7
#define TT   49
#define NN   3136            // H*W
#define MM   (B_ * NN)       // 200704
#define SCALE 0.17677669529663687f

typedef short bf16x8 __attribute__((ext_vector_type(8)));   // 8 bf16 (4 VGPRs)
typedef float f32x4  __attribute__((ext_vector_type(4)));
typedef unsigned short u16;

__device__ __forceinline__ float bf2f(u16 u) {
    return __uint_as_float(((unsigned int)u) << 16);
}
__device__ __forceinline__ u16 f2bf(float f) {
    unsigned int u = __float_as_uint(f);
    u += 0x7FFFu + ((u >> 16) & 1u);   // round-to-nearest-even
    return (u16)(u >> 16);
}

// ---------------------------------------------------------------------------
// KA: fused qkv-GEMM + windowed attention, MFMA. One block per (b, window).
// LDS arena: [0]=x window, [1]=q, [2]=k, [3]=v (each 64x136 u16 = 17,408 B,
// total 69,632 B -> 2 blocks/CU). P (4 heads x 64x64 bf16 = 32,768 B)
// overlays the q+k slabs after q/k frags are in registers (barrier-protected).
// w_qkv B-fragments are converted f32->bf16 straight from global (L2-res).
// ---------------------------------------------------------------------------
__global__ __launch_bounds__(256) void ka_fused(
    const float* __restrict__ x, const float* __restrict__ wqkv,
    u16* __restrict__ vout, float* __restrict__ out)
{
    __shared__ u16 arena[4][64][136];
    u16* ps_ = &arena[1][0][0];     // 32,768 B overlay on q+k slabs (34,816 B)

    const int t   = threadIdx.x;
    const int blk = blockIdx.x;
    const int b_  = blk >> 6, wr = blk & 63;
    const int qy  = wr >> 3, qx = wr & 7;
    const int wave = t >> 6, lane = t & 63, lr = lane & 15, quad = lane >> 4;

    // ---- phase 0: stage x window -> arena[0] (bf16), zero pad rows ----
    for (int i = t; i < 64 * 32; i += 256) {
        int tok = i >> 5, c4 = (i & 31) * 4;
        ushort4 u4 = {0, 0, 0, 0};
        if (tok < TT) {
            int hh = qy * WSZ + tok / WSZ, ww = qx * WSZ + tok % WSZ;
            float4 f = *(const float4*)&x[((size_t)b_ * NN + hh * W_ + ww) * C_ + c4];
            u4.x = f2bf(f.x); u4.y = f2bf(f.y);
            u4.z = f2bf(f.z); u4.w = f2bf(f.w);
        }
        *(ushort4*)&arena[0][tok][c4] = u4;
    }
    __syncthreads();

    // ---- phase 1: q/k/v = x @ w_chunk^T; B-frags direct from global.
    // Each wave owns output cols [half*64+wave*16, +16) -> no barriers. ----
    for (int ch = 0; ch < 3; ch++) {
        const float mul = (ch == 0) ? SCALE : 1.0f;
        u16 (*dst)[136] = arena[1 + ch];
#pragma unroll
        for (int half = 0; half < 2; half++) {
            const float* wrow =
                &wqkv[(size_t)(ch * 128 + half * 64 + wave * 16 + lr) * C_];
            f32x4 acc[4];
#pragma unroll
            for (int mi = 0; mi < 4; mi++) acc[mi] = {0.f, 0.f, 0.f, 0.f};
#pragma unroll
            for (int kk = 0; kk < 4; kk++) {
                float4 f0 = *(const float4*)&wrow[kk * 32 + quad * 8];
                float4 f1 = *(const float4*)&wrow[kk * 32 + quad * 8 + 4];
                bf16x8 bfr;
                bfr[0] = (short)f2bf(f0.x); bfr[1] = (short)f2bf(f0.y);
                bfr[2] = (short)f2bf(f0.z); bfr[3] = (short)f2bf(f0.w);
                bfr[4] = (short)f2bf(f1.x); bfr[5] = (short)f2bf(f1.y);
                bfr[6] = (short)f2bf(f1.z); bfr[7] = (short)f2bf(f1.w);
#pragma unroll
                for (int mi = 0; mi < 4; mi++) {
                    bf16x8 afr = *(const bf16x8*)&arena[0][mi * 16 + lr][kk * 32 + quad * 8];
                    acc[mi] = __builtin_amdgcn_mfma_f32_16x16x32_bf16(
                        afr, bfr, acc[mi], 0, 0, 0);
                }
            }
#pragma unroll
            for (int mi = 0; mi < 4; mi++) {
#pragma unroll
                for (int r = 0; r < 4; r++) {
                    int tok = mi * 16 + quad * 4 + r;
                    int col = half * 64 + wave * 16 + lr;
                    u16 bv = f2bf(acc[mi][r] * mul);
                    dst[tok][col] = bv;
                    if (ch == 2 && tok < TT)
                        vout[((size_t)b_ * NN + wr * TT + tok) * C_ + col] = bv;
                }
            }
        }
    }
    __syncthreads();   // publish q/k/v to all waves

    // ---- phase 2: attention, wave = head ----
    const int h = wave;
    bf16x8 qf[4], kf[4];
#pragma unroll
    for (int mi = 0; mi < 4; mi++) {
        qf[mi] = *(const bf16x8*)&arena[1][mi * 16 + lr][h * 32 + quad * 8];
        kf[mi] = *(const bf16x8*)&arena[2][mi * 16 + lr][h * 32 + quad * 8];
    }
    __syncthreads();   // all waves hold q/k frags -> ps overlay now safe

    f32x4 s[4][4];
#pragma unroll
    for (int mi = 0; mi < 4; mi++)
#pragma unroll
        for (int nj = 0; nj < 4; nj++) s[mi][nj] = {0.f, 0.f, 0.f, 0.f};
#pragma unroll
    for (int mi = 0; mi < 4; mi++)
#pragma unroll
        for (int nj = 0; nj < 4; nj++)
            s[mi][nj] = __builtin_amdgcn_mfma_f32_16x16x32_bf16(
                qf[mi], kf[nj], s[mi][nj], 0, 0, 0);

    // mask pad key columns j = 48 + lr, lr >= 1
    if (lr >= 1) {
#pragma unroll
        for (int mi = 0; mi < 4; mi++)
#pragma unroll
            for (int r = 0; r < 4; r++) s[mi][3][r] = -1e30f;
    }

    float rsum[4][4];
#pragma unroll
    for (int mi = 0; mi < 4; mi++) {
#pragma unroll
        for (int r = 0; r < 4; r++) {
            float mx = fmaxf(fmaxf(s[mi][0][r], s[mi][1][r]),
                             fmaxf(s[mi][2][r], s[mi][3][r]));
#pragma unroll
            for (int off = 1; off < 16; off <<= 1)
                mx = fmaxf(mx, __shfl_xor(mx, off));
            float sum = 0.f;
#pragma unroll
            for (int nj = 0; nj < 4; nj++) {
                float p = __expf(s[mi][nj][r] - mx);
                s[mi][nj][r] = p;
                sum += p;
            }
#pragma unroll
            for (int off = 1; off < 16; off <<= 1)
                sum += __shfl_xor(sum, off);
            rsum[mi][r] = sum;
        }
    }

    // P: C-layout -> LDS (overlay, stride 64) -> A-layout (intra-wave)
#pragma unroll
    for (int mi = 0; mi < 4; mi++)
#pragma unroll
        for (int nj = 0; nj < 4; nj++)
#pragma unroll
            for (int r = 0; r < 4; r++)
                ps_[((h * 64) + mi * 16 + quad * 4 + r) * 64 + nj * 16 + lr] =
                    f2bf(s[mi][nj][r]);

    f32x4 o[4][2];
#pragma unroll
    for (int mi = 0; mi < 4; mi++)
#pragma unroll
        for (int nv = 0; nv < 2; nv++) o[mi][nv] = {0.f, 0.f, 0.f, 0.f};

#pragma unroll
    for (int kt = 0; kt < 2; kt++) {
        bf16x8 pf[4];
#pragma unroll
        for (int mi = 0; mi < 4; mi++)
            pf[mi] = *(const bf16x8*)&ps_[((h * 64) + mi * 16 + lr) * 64 +
                                          kt * 32 + quad * 8];
        bf16x8 vf[2];
#pragma unroll
        for (int nv = 0; nv < 2; nv++) {
            bf16x8 tmp;
#pragma unroll
            for (int jj = 0; jj < 8; jj++)
                tmp[jj] = (short)arena[3][kt * 32 + quad * 8 + jj][h * 32 + nv * 16 + lr];
            vf[nv] = tmp;
        }
#pragma unroll
        for (int mi = 0; mi < 4; mi++)
#pragma unroll
            for (int nv = 0; nv < 2; nv++)
                o[mi][nv] = __builtin_amdgcn_mfma_f32_16x16x32_bf16(
                    pf[mi], vf[nv], o[mi][nv], 0, 0, 0);
    }

#pragma unroll
    for (int mi = 0; mi < 4; mi++) {
#pragma unroll
        for (int r = 0; r < 4; r++) {
            int i = mi * 16 + quad * 4 + r;
            if (i < TT) {
                int hh = qy * WSZ + i / WSZ, ww = qx * WSZ + i % WSZ;
                size_t orow = (size_t)b_ * NN + hh * W_ + ww;
                float inv = 1.f / rsum[mi][r];
#pragma unroll
                for (int nv = 0; nv < 2; nv++)
                    out[orow * C_ + h * 32 + nv * 16 + lr] = o[mi][nv][r] * inv;
            }
        }
    }
}

// ---------------------------------------------------------------------------
// KB: depthwise 3x3 conv on bf16 v (windowed layout) + f32 bias/weights,
// accumulate f32 into d_out (B,N,C)   [round-2 verified]
// ---------------------------------------------------------------------------
__global__ __launch_bounds__(256) void kb_lim(
    const u16* __restrict__ v, const float* __restrict__ wlim,
    const float* __restrict__ blim, float* __restrict__ out)
{
    int idx = blockIdx.x * 256 + threadIdx.x;     // < MM*C_
    int c  = idx & 127;
    int p  = idx >> 7;
    int ww = p % W_;
    int p2 = p / W_;
    int hh = p2 % H_;
    int b_ = p2 / H_;
    float acc = blim[c];
#pragma unroll
    for (int dy = -1; dy <= 1; dy++) {
        int y = hh + dy;
        if (y < 0 || y >= H_) continue;
        int qy = y / WSZ, ry = y - qy * WSZ;
#pragma unroll
        for (int dx = -1; dx <= 1; dx++) {
            int x2 = ww + dx;
            if (x2 < 0 || x2 >= W_) continue;
            int qx = x2 / WSZ, rx = x2 - qx * WSZ;
            size_t vrow = (size_t)b_ * NN + (qy * 8 + qx) * TT + ry * WSZ + rx;
            acc += bf2f(v[vrow * C_ + c]) * wlim[c * 9 + (dy + 1) * 3 + (dx + 1)];
        }
    }
    out[idx] = out[idx] + acc;
}

// ---------------------------------------------------------------------------
// KC: out = y @ w_proj^T + b_proj, MFMA gemm_bt, f32 I/O staged to bf16.
// FIXED: acc[4][4] / ni 0..3 -> each n-wave covers its FULL 64 columns
// (round 1/3 bug: acc[4][2] left cols [32,64)+[96,128) unwritten).
// ---------------------------------------------------------------------------
__global__ __launch_bounds__(256) void kc_proj(
    float* __restrict__ y, const float* __restrict__ wproj,
    const float* __restrict__ bproj)
{
    __shared__ u16 As[128][72];
    __shared__ u16 Ws[128][72];
    const int t    = threadIdx.x;
    const int m0   = blockIdx.x * 128;
    const int wave = t >> 6, lane = t & 63, lr = lane & 15, quad = lane >> 4;
    const int wm = (wave >> 1) * 64, wn = (wave & 1) * 64;

    f32x4 acc[4][4];
#pragma unroll
    for (int mi = 0; mi < 4; mi++)
#pragma unroll
        for (int ni = 0; ni < 4; ni++) acc[mi][ni] = {0.f, 0.f, 0.f, 0.f};

#pragma unroll
    for (int kt = 0; kt < 2; kt++) {
        const int k0 = kt * 64;
#pragma unroll
        for (int p = 0; p < 8; p++) {
            int e   = p * 256 + t;
            int row = e >> 4;
            int col = (e & 15) * 4;
            float4 fa = *(const float4*)&y[(size_t)(m0 + row) * C_ + k0 + col];
            ushort4 ua;
            ua.x = f2bf(fa.x); ua.y = f2bf(fa.y);
            ua.z = f2bf(fa.z); ua.w = f2bf(fa.w);
            *(ushort4*)&As[row][col] = ua;
            float4 fw = *(const float4*)&wproj[(size_t)row * C_ + k0 + col];
            ushort4 uw;
            uw.x = f2bf(fw.x); uw.y = f2bf(fw.y);
            uw.z = f2bf(fw.z); uw.w = f2bf(fw.w);
            *(ushort4*)&Ws[row][col] = uw;
        }
        __syncthreads();
#pragma unroll
        for (int kk = 0; kk < 2; kk++) {
            bf16x8 a[4], b[4];
#pragma unroll
            for (int mi = 0; mi < 4; mi++)
                a[mi] = *(const bf16x8*)&As[wm + mi * 16 + lr][kk * 32 + quad * 8];
#pragma unroll
            for (int ni = 0; ni < 4; ni++)
                b[ni] = *(const bf16x8*)&Ws[wn + ni * 16 + lr][kk * 32 + quad * 8];
#pragma unroll
            for (int mi = 0; mi < 4; mi++)
#pragma unroll
                for (int ni = 0; ni < 4; ni++)
                    acc[mi][ni] = __builtin_amdgcn_mfma_f32_16x16x32_bf16(
                        a[mi], b[ni], acc[mi][ni], 0, 0, 0);
        }
        if (kt == 0) __syncthreads();
    }

#pragma unroll
    for (int mi = 0; mi < 4; mi++) {
#pragma unroll
        for (int r = 0; r < 4; r++) {
            int m = m0 + wm + mi * 16 + quad * 4 + r;
#pragma unroll
            for (int ni = 0; ni < 4; ni++) {
                int c = wn + ni * 16 + lr;
                y[(size_t)m * C_ + c] = acc[mi][ni][r] + bproj[c];
            }
        }
    }
}

extern "C" void kernel_launch(void* const* d_in, const int* in_sizes, int n_in,
                              void* d_out, int out_size, void* d_ws, size_t ws_size,
                              hipStream_t stream)
{
    const float* x     = (const float*)d_in[0];
    const float* wqkv  = (const float*)d_in[1];
    const float* wlim  = (const float*)d_in[2];
    const float* blim  = (const float*)d_in[3];
    const float* wproj = (const float*)d_in[4];
    const float* bproj = (const float*)d_in[5];
    float* out = (float*)d_out;
    u16*   v   = (u16*)d_ws;            // 51.4 MB (round-2-proven footprint)

    ka_fused<<<dim3(B_ * 64), 256, 0, stream>>>(x, wqkv, v, out);
    kb_lim  <<<dim3(MM * C_ / 256), 256, 0, stream>>>(v, wlim, blim, out);
    kc_proj <<<dim3(MM / 128), 256, 0, stream>>>(out, wproj, bproj);
}